// Round 2
// baseline (1140.737 us; speedup 1.0000x reference)
//
#include <hip/hip_runtime.h>
#include <hip/hip_bf16.h>

#define NN 50000
#define EE 800000
#define GG 64
// D=128, H=8, C=16, L=3

// ---------------------------------------------------------------- CSR build
__global__ __launch_bounds__(256) void hist_kernel(const int* __restrict__ dst,
                                                   int* __restrict__ counts) {
    int e = blockIdx.x * 256 + threadIdx.x;
    if (e < EE) atomicAdd(&counts[dst[e]], 1);
}

__global__ __launch_bounds__(1024) void scan_kernel(const int* __restrict__ counts,
                                                    int* __restrict__ offsets) {
    __shared__ int part[1024];
    const int t = threadIdx.x;
    const int CH = (NN + 1023) / 1024;  // 49
    const int st = t * CH;
    int s = 0;
    for (int i = 0; i < CH; ++i) {
        int idx = st + i;
        if (idx < NN) s += counts[idx];
    }
    part[t] = s;
    __syncthreads();
    for (int off = 1; off < 1024; off <<= 1) {
        int val = (t >= off) ? part[t - off] : 0;
        __syncthreads();
        part[t] += val;
        __syncthreads();
    }
    int run = (t == 0) ? 0 : part[t - 1];  // exclusive base for this chunk
    for (int i = 0; i < CH; ++i) {
        int idx = st + i;
        if (idx < NN) { offsets[idx] = run; run += counts[idx]; }
    }
    if (t == 1023) offsets[NN] = part[1023];
}

__global__ __launch_bounds__(256) void scatter_kernel(const int* __restrict__ src,
                                                      const int* __restrict__ dst,
                                                      const int* __restrict__ offs,
                                                      int* __restrict__ cursor,
                                                      int* __restrict__ csrc) {
    int e = blockIdx.x * 256 + threadIdx.x;
    if (e < EE) {
        int dn = dst[e];
        int p = atomicAdd(&cursor[dn], 1);
        csrc[offs[dn] + p] = src[e];
    }
}

__global__ __launch_bounds__(256) void starts_kernel(const int* __restrict__ batch,
                                                     int* __restrict__ starts) {
    int i = blockIdx.x * 256 + threadIdx.x;
    if (i > NN) return;
    int b  = (i < NN) ? batch[i] : GG;
    int bp = (i == 0) ? -1 : batch[i - 1];
    for (int g = bp + 1; g <= b && g <= GG; ++g) starts[g] = i;
}

// ---------------------------------------------------------------- fused QKV+skip GEMM
// out[n, j] = sum_i x[n,i] * W[i,j] + b[j] for each of the 4 weight matrices.
// Tile: 32 nodes x 128 cols per block; K chunked by 32. 32KB LDS.
__global__ __launch_bounds__(256)
void gemm_qkvs(const float* __restrict__ xin,
               const float* __restrict__ Wq, const float* __restrict__ bq,
               const float* __restrict__ Wk, const float* __restrict__ bk,
               const float* __restrict__ Wv, const float* __restrict__ bv,
               const float* __restrict__ Ws, const float* __restrict__ bs,
               float* __restrict__ q, float* __restrict__ k,
               float* __restrict__ v, float* __restrict__ xs) {
    __shared__ float wl[32 * 128];
    __shared__ float xl[32 * 128];
    const int t = threadIdx.x;
    const int m = blockIdx.y;
    const float* W; const float* b; float* out;
    switch (m) {
        case 0:  W = Wq; b = bq; out = q;  break;
        case 1:  W = Wk; b = bk; out = k;  break;
        case 2:  W = Wv; b = bv; out = v;  break;
        default: W = Ws; b = bs; out = xs; break;
    }
    const int n0 = blockIdx.x * 32;
    float4* xl4 = (float4*)xl;
    const float4* X4 = (const float4*)xin;
    for (int i = t; i < 1024; i += 256) {          // 32 rows x 32 float4
        int node = n0 + (i >> 5);
        float4 val = make_float4(0.f, 0.f, 0.f, 0.f);
        if (node < NN) val = X4[node * 32 + (i & 31)];
        xl4[i] = val;
    }
    const int cg = t & 31;   // 32 col groups of 4  -> cols cg*4..cg*4+3
    const int ng = t >> 5;   // 8 node groups of 4  -> nodes ng*4..ng*4+3
    float4 acc[4] = {};
    float4* wl4 = (float4*)wl;
    const float4* W4 = (const float4*)W;
    for (int kc = 0; kc < 4; ++kc) {
        __syncthreads();
        for (int i = t; i < 1024; i += 256) wl4[i] = W4[kc * 1024 + i];
        __syncthreads();
        #pragma unroll
        for (int k0 = 0; k0 < 32; k0 += 4) {
            float4 w0 = *(const float4*)&wl[(k0 + 0) * 128 + cg * 4];
            float4 w1 = *(const float4*)&wl[(k0 + 1) * 128 + cg * 4];
            float4 w2 = *(const float4*)&wl[(k0 + 2) * 128 + cg * 4];
            float4 w3 = *(const float4*)&wl[(k0 + 3) * 128 + cg * 4];
            #pragma unroll
            for (int r = 0; r < 4; ++r) {
                const float4 xv = *(const float4*)&xl[(ng * 4 + r) * 128 + kc * 32 + k0];
                acc[r].x += xv.x * w0.x + xv.y * w1.x + xv.z * w2.x + xv.w * w3.x;
                acc[r].y += xv.x * w0.y + xv.y * w1.y + xv.z * w2.y + xv.w * w3.y;
                acc[r].z += xv.x * w0.z + xv.y * w1.z + xv.z * w2.z + xv.w * w3.z;
                acc[r].w += xv.x * w0.w + xv.y * w1.w + xv.z * w2.w + xv.w * w3.w;
            }
        }
    }
    float4 bb = *(const float4*)&b[cg * 4];
    #pragma unroll
    for (int r = 0; r < 4; ++r) {
        int node = n0 + ng * 4 + r;
        if (node < NN) {
            float4 o = make_float4(acc[r].x + bb.x, acc[r].y + bb.y,
                                   acc[r].z + bb.z, acc[r].w + bb.w);
            *((float4*)&out[node * 128 + cg * 4]) = o;
        }
    }
}

// ---------------------------------------------------------------- attention (CSR, online softmax)
// thread = (node, head); 8 threads of a wave cover one node's 8 heads.
__global__ __launch_bounds__(256)
void attn_kernel(const float* __restrict__ q, const float* __restrict__ k,
                 const float* __restrict__ v, float* __restrict__ xio,
                 const int* __restrict__ offs, const int* __restrict__ csrc) {
    const int t = threadIdx.x;
    const int h = t & 7;
    const int n = blockIdx.x * 32 + (t >> 3);
    if (n >= NN) return;
    const float4* qp = (const float4*)(q + n * 128 + h * 16);
    const float4 q0 = qp[0], q1 = qp[1], q2 = qp[2], q3 = qp[3];
    float m = -__builtin_inff();
    float d = 0.f;
    float4 a0 = {}, a1 = {}, a2 = {}, a3 = {};
    const int e0 = offs[n], e1 = offs[n + 1];
    for (int e = e0; e < e1; ++e) {
        const int s = csrc[e];
        const float4* kp = (const float4*)(k + s * 128 + h * 16);
        const float4 k0 = kp[0], k1 = kp[1], k2 = kp[2], k3 = kp[3];
        float dot = q0.x * k0.x + q0.y * k0.y + q0.z * k0.z + q0.w * k0.w
                  + q1.x * k1.x + q1.y * k1.y + q1.z * k1.z + q1.w * k1.w
                  + q2.x * k2.x + q2.y * k2.y + q2.z * k2.z + q2.w * k2.w
                  + q3.x * k3.x + q3.y * k3.y + q3.z * k3.z + q3.w * k3.w;
        const float alpha = dot * 0.25f;                 // / sqrt(C=16)
        const float nm = fmaxf(m, alpha);
        const float scale = __expf(m - nm);              // 0 on first edge (m=-inf)
        const float p = __expf(alpha - nm);
        d = d * scale + p;
        const float4* vp = (const float4*)(v + s * 128 + h * 16);
        const float4 v0 = vp[0], v1 = vp[1], v2 = vp[2], v3 = vp[3];
        a0.x = a0.x * scale + p * v0.x; a0.y = a0.y * scale + p * v0.y;
        a0.z = a0.z * scale + p * v0.z; a0.w = a0.w * scale + p * v0.w;
        a1.x = a1.x * scale + p * v1.x; a1.y = a1.y * scale + p * v1.y;
        a1.z = a1.z * scale + p * v1.z; a1.w = a1.w * scale + p * v1.w;
        a2.x = a2.x * scale + p * v2.x; a2.y = a2.y * scale + p * v2.y;
        a2.z = a2.z * scale + p * v2.z; a2.w = a2.w * scale + p * v2.w;
        a3.x = a3.x * scale + p * v3.x; a3.y = a3.y * scale + p * v3.y;
        a3.z = a3.z * scale + p * v3.z; a3.w = a3.w * scale + p * v3.w;
        m = nm;
    }
    const float inv = 1.f / (d + 1e-16f);
    float4* op = (float4*)(xio + n * 128 + h * 16);
    float4 o0 = op[0], o1 = op[1], o2 = op[2], o3 = op[3];
    o0.x += a0.x * inv; o0.y += a0.y * inv; o0.z += a0.z * inv; o0.w += a0.w * inv;
    o1.x += a1.x * inv; o1.y += a1.y * inv; o1.z += a1.z * inv; o1.w += a1.w * inv;
    o2.x += a2.x * inv; o2.y += a2.y * inv; o2.z += a2.z * inv; o2.w += a2.w * inv;
    o3.x += a3.x * inv; o3.y += a3.y * inv; o3.z += a3.z * inv; o3.w += a3.w * inv;
    op[0] = o0; op[1] = o1; op[2] = o2; op[3] = o3;
}

// ---------------------------------------------------------------- readout
__global__ __launch_bounds__(256)
void score_kernel(const float* __restrict__ x, const float* __restrict__ wg,
                  const float* __restrict__ bg, float* __restrict__ score) {
    const int lane = threadIdx.x & 63;
    const int wid = blockIdx.x * 4 + (threadIdx.x >> 6);
    const int nw = gridDim.x * 4;
    const float2 w2 = ((const float2*)wg)[lane];
    const float b = bg[0];
    for (int n = wid; n < NN; n += nw) {
        const float2 xv = ((const float2*)(x + n * 128))[lane];
        float p = xv.x * w2.x + xv.y * w2.y;
        #pragma unroll
        for (int o = 32; o; o >>= 1) p += __shfl_xor(p, o);
        if (lane == 0) score[n] = 1.f / (1.f + __expf(-(p + b)));
    }
}

__global__ __launch_bounds__(128)
void pool_kernel(const float* __restrict__ x, const float* __restrict__ score,
                 const int* __restrict__ starts, float* __restrict__ out) {
    const int g = blockIdx.x, c = threadIdx.x;
    const int s0 = starts[g], s1 = starts[g + 1];
    float sum = 0.f, mx = -__builtin_inff();
    for (int n = s0; n < s1; ++n) {
        const float xv = x[n * 128 + c];
        sum += score[n] * xv;
        mx = fmaxf(mx, xv);
    }
    out[g * 256 + c] = sum;
    out[g * 256 + 128 + c] = mx;
}

// ---------------------------------------------------------------- launch
extern "C" void kernel_launch(void* const* d_in, const int* in_sizes, int n_in,
                              void* d_out, int out_size, void* d_ws, size_t ws_size,
                              hipStream_t stream) {
    const float* x     = (const float*)d_in[0];
    const int*   ei    = (const int*)d_in[1];
    const int*   batch = (const int*)d_in[2];
    const float* Wq = (const float*)d_in[3];
    const float* bq = (const float*)d_in[4];
    const float* Wk = (const float*)d_in[5];
    const float* bk = (const float*)d_in[6];
    const float* Wv = (const float*)d_in[7];
    const float* bv = (const float*)d_in[8];
    const float* Ws = (const float*)d_in[9];
    const float* bs = (const float*)d_in[10];
    const float* wg = (const float*)d_in[11];
    const float* bg = (const float*)d_in[12];
    float* out = (float*)d_out;

    char* w = (char*)d_ws;
    float* qb    = (float*)w; w += (size_t)NN * 128 * 4;
    float* kb    = (float*)w; w += (size_t)NN * 128 * 4;
    float* vb    = (float*)w; w += (size_t)NN * 128 * 4;
    float* bufA  = (float*)w; w += (size_t)NN * 128 * 4;
    float* bufB  = (float*)w; w += (size_t)NN * 128 * 4;
    float* score = (float*)w; w += (size_t)NN * 4;
    int* counts  = (int*)w;   w += (size_t)NN * 4;
    int* offsets = (int*)w;   w += (size_t)(NN + 1) * 4;
    int* csrc    = (int*)w;   w += (size_t)EE * 4;
    int* starts  = (int*)w;   w += (size_t)(GG + 1) * 4;

    const int* srcI = ei;
    const int* dstI = ei + EE;

    // CSR over dst (reused by all 3 layers)
    hipMemsetAsync(counts, 0, (size_t)NN * 4, stream);
    hist_kernel<<<(EE + 255) / 256, 256, 0, stream>>>(dstI, counts);
    scan_kernel<<<1, 1024, 0, stream>>>(counts, offsets);
    hipMemsetAsync(counts, 0, (size_t)NN * 4, stream);  // reuse as cursor
    scatter_kernel<<<(EE + 255) / 256, 256, 0, stream>>>(srcI, dstI, offsets, counts, csrc);
    starts_kernel<<<(NN + 256) / 256, 256, 0, stream>>>(batch, starts);

    const float* xin = x;
    float* bufs[2] = {bufA, bufB};
    const int nodeBlocks = (NN + 31) / 32;  // 1563
    for (int l = 0; l < 3; ++l) {
        float* xs = bufs[l & 1];
        gemm_qkvs<<<dim3(nodeBlocks, 4), 256, 0, stream>>>(
            xin,
            Wq + (size_t)l * 16384, bq + (size_t)l * 128,
            Wk + (size_t)l * 16384, bk + (size_t)l * 128,
            Wv + (size_t)l * 16384, bv + (size_t)l * 128,
            Ws + (size_t)l * 16384, bs + (size_t)l * 128,
            qb, kb, vb, xs);
        attn_kernel<<<nodeBlocks, 256, 0, stream>>>(qb, kb, vb, xs, offsets, csrc);
        xin = xs;
    }

    score_kernel<<<1024, 256, 0, stream>>>(xin, wg, bg, score);
    pool_kernel<<<GG, 128, 0, stream>>>(xin, score, starts, out);
}

// Round 3
// 972.871 us; speedup vs baseline: 1.1725x; 1.1725x over previous
//
#include <hip/hip_runtime.h>
#include <hip/hip_bf16.h>

#define NN 50000
#define EE 800000
#define GG 64
#define PCH 16   // pooling chunks per graph
// D=128, H=8, C=16, L=3

// ---------------------------------------------------------------- CSR build
__global__ __launch_bounds__(256) void hist_kernel(const int* __restrict__ dst,
                                                   int* __restrict__ counts) {
    int e = blockIdx.x * 256 + threadIdx.x;
    if (e < EE) atomicAdd(&counts[dst[e]], 1);
}

__global__ __launch_bounds__(1024) void scan_kernel(const int* __restrict__ counts,
                                                    int* __restrict__ offsets) {
    __shared__ int part[1024];
    const int t = threadIdx.x;
    const int CH = (NN + 1023) / 1024;  // 49
    const int st = t * CH;
    int s = 0;
    for (int i = 0; i < CH; ++i) {
        int idx = st + i;
        if (idx < NN) s += counts[idx];
    }
    part[t] = s;
    __syncthreads();
    for (int off = 1; off < 1024; off <<= 1) {
        int val = (t >= off) ? part[t - off] : 0;
        __syncthreads();
        part[t] += val;
        __syncthreads();
    }
    int run = (t == 0) ? 0 : part[t - 1];  // exclusive base for this chunk
    for (int i = 0; i < CH; ++i) {
        int idx = st + i;
        if (idx < NN) { offsets[idx] = run; run += counts[idx]; }
    }
    if (t == 1023) offsets[NN] = part[1023];
}

__global__ __launch_bounds__(256) void scatter_kernel(const int* __restrict__ src,
                                                      const int* __restrict__ dst,
                                                      const int* __restrict__ offs,
                                                      int* __restrict__ cursor,
                                                      int* __restrict__ csrc) {
    int e = blockIdx.x * 256 + threadIdx.x;
    if (e < EE) {
        int dn = dst[e];
        int p = atomicAdd(&cursor[dn], 1);
        csrc[offs[dn] + p] = src[e];
    }
}

__global__ __launch_bounds__(256) void starts_kernel(const int* __restrict__ batch,
                                                     int* __restrict__ starts) {
    int i = blockIdx.x * 256 + threadIdx.x;
    if (i > NN) return;
    int b  = (i < NN) ? batch[i] : GG;
    int bp = (i == 0) ? -1 : batch[i - 1];
    for (int g = bp + 1; g <= b && g <= GG; ++g) starts[g] = i;
}

// ---------------------------------------------------------------- fused QKV+skip GEMM
__global__ __launch_bounds__(256)
void gemm_qkvs(const float* __restrict__ xin,
               const float* __restrict__ Wq, const float* __restrict__ bq,
               const float* __restrict__ Wk, const float* __restrict__ bk,
               const float* __restrict__ Wv, const float* __restrict__ bv,
               const float* __restrict__ Ws, const float* __restrict__ bs,
               float* __restrict__ q, float* __restrict__ k,
               float* __restrict__ v, float* __restrict__ xs) {
    __shared__ float wl[32 * 128];
    __shared__ float xl[32 * 128];
    const int t = threadIdx.x;
    const int m = blockIdx.y;
    const float* W; const float* b; float* out;
    switch (m) {
        case 0:  W = Wq; b = bq; out = q;  break;
        case 1:  W = Wk; b = bk; out = k;  break;
        case 2:  W = Wv; b = bv; out = v;  break;
        default: W = Ws; b = bs; out = xs; break;
    }
    const int n0 = blockIdx.x * 32;
    float4* xl4 = (float4*)xl;
    const float4* X4 = (const float4*)xin;
    for (int i = t; i < 1024; i += 256) {          // 32 rows x 32 float4
        int node = n0 + (i >> 5);
        float4 val = make_float4(0.f, 0.f, 0.f, 0.f);
        if (node < NN) val = X4[node * 32 + (i & 31)];
        xl4[i] = val;
    }
    const int cg = t & 31;   // cols cg*4..cg*4+3
    const int ng = t >> 5;   // nodes ng*4..ng*4+3
    float4 acc[4] = {};
    float4* wl4 = (float4*)wl;
    const float4* W4 = (const float4*)W;
    for (int kc = 0; kc < 4; ++kc) {
        __syncthreads();
        for (int i = t; i < 1024; i += 256) wl4[i] = W4[kc * 1024 + i];
        __syncthreads();
        #pragma unroll
        for (int k0 = 0; k0 < 32; k0 += 4) {
            float4 w0 = *(const float4*)&wl[(k0 + 0) * 128 + cg * 4];
            float4 w1 = *(const float4*)&wl[(k0 + 1) * 128 + cg * 4];
            float4 w2 = *(const float4*)&wl[(k0 + 2) * 128 + cg * 4];
            float4 w3 = *(const float4*)&wl[(k0 + 3) * 128 + cg * 4];
            #pragma unroll
            for (int r = 0; r < 4; ++r) {
                const float4 xv = *(const float4*)&xl[(ng * 4 + r) * 128 + kc * 32 + k0];
                acc[r].x += xv.x * w0.x + xv.y * w1.x + xv.z * w2.x + xv.w * w3.x;
                acc[r].y += xv.x * w0.y + xv.y * w1.y + xv.z * w2.y + xv.w * w3.y;
                acc[r].z += xv.x * w0.z + xv.y * w1.z + xv.z * w2.z + xv.w * w3.z;
                acc[r].w += xv.x * w0.w + xv.y * w1.w + xv.z * w2.w + xv.w * w3.w;
            }
        }
    }
    float4 bb = *(const float4*)&b[cg * 4];
    #pragma unroll
    for (int r = 0; r < 4; ++r) {
        int node = n0 + ng * 4 + r;
        if (node < NN) {
            float4 o = make_float4(acc[r].x + bb.x, acc[r].y + bb.y,
                                   acc[r].z + bb.z, acc[r].w + bb.w);
            *((float4*)&out[node * 128 + cg * 4]) = o;
        }
    }
}

// ---------------------------------------------------------------- attention (CSR, online softmax)
__global__ __launch_bounds__(256)
void attn_kernel(const float* __restrict__ q, const float* __restrict__ k,
                 const float* __restrict__ v, float* __restrict__ xio,
                 const int* __restrict__ offs, const int* __restrict__ csrc) {
    const int t = threadIdx.x;
    const int h = t & 7;
    const int n = blockIdx.x * 32 + (t >> 3);
    if (n >= NN) return;
    const float4* qp = (const float4*)(q + n * 128 + h * 16);
    const float4 q0 = qp[0], q1 = qp[1], q2 = qp[2], q3 = qp[3];
    float m = -__builtin_inff();
    float d = 0.f;
    float4 a0 = {}, a1 = {}, a2 = {}, a3 = {};
    const int e0 = offs[n], e1 = offs[n + 1];
    for (int e = e0; e < e1; ++e) {
        const int s = csrc[e];
        const float4* kp = (const float4*)(k + s * 128 + h * 16);
        const float4 k0 = kp[0], k1 = kp[1], k2 = kp[2], k3 = kp[3];
        float dot = q0.x * k0.x + q0.y * k0.y + q0.z * k0.z + q0.w * k0.w
                  + q1.x * k1.x + q1.y * k1.y + q1.z * k1.z + q1.w * k1.w
                  + q2.x * k2.x + q2.y * k2.y + q2.z * k2.z + q2.w * k2.w
                  + q3.x * k3.x + q3.y * k3.y + q3.z * k3.z + q3.w * k3.w;
        const float alpha = dot * 0.25f;                 // / sqrt(C=16)
        const float nm = fmaxf(m, alpha);
        const float scale = __expf(m - nm);              // 0 on first edge
        const float p = __expf(alpha - nm);
        d = d * scale + p;
        const float4* vp = (const float4*)(v + s * 128 + h * 16);
        const float4 v0 = vp[0], v1 = vp[1], v2 = vp[2], v3 = vp[3];
        a0.x = a0.x * scale + p * v0.x; a0.y = a0.y * scale + p * v0.y;
        a0.z = a0.z * scale + p * v0.z; a0.w = a0.w * scale + p * v0.w;
        a1.x = a1.x * scale + p * v1.x; a1.y = a1.y * scale + p * v1.y;
        a1.z = a1.z * scale + p * v1.z; a1.w = a1.w * scale + p * v1.w;
        a2.x = a2.x * scale + p * v2.x; a2.y = a2.y * scale + p * v2.y;
        a2.z = a2.z * scale + p * v2.z; a2.w = a2.w * scale + p * v2.w;
        a3.x = a3.x * scale + p * v3.x; a3.y = a3.y * scale + p * v3.y;
        a3.z = a3.z * scale + p * v3.z; a3.w = a3.w * scale + p * v3.w;
        m = nm;
    }
    const float inv = 1.f / (d + 1e-16f);
    float4* op = (float4*)(xio + n * 128 + h * 16);
    float4 o0 = op[0], o1 = op[1], o2 = op[2], o3 = op[3];
    o0.x += a0.x * inv; o0.y += a0.y * inv; o0.z += a0.z * inv; o0.w += a0.w * inv;
    o1.x += a1.x * inv; o1.y += a1.y * inv; o1.z += a1.z * inv; o1.w += a1.w * inv;
    o2.x += a2.x * inv; o2.y += a2.y * inv; o2.z += a2.z * inv; o2.w += a2.w * inv;
    o3.x += a3.x * inv; o3.y += a3.y * inv; o3.z += a3.z * inv; o3.w += a3.w * inv;
    op[0] = o0; op[1] = o1; op[2] = o2; op[3] = o3;
}

// ---------------------------------------------------------------- readout (2-phase, fused gate)
// Phase A: 64 graphs x PCH chunks, 128 threads. Fuses sigmoid(x@wg+b) with
// partial gated-sum and partial max. Deterministic (no atomics).
__global__ __launch_bounds__(128)
void pool_partial(const float* __restrict__ x, const float* __restrict__ wg,
                  const float* __restrict__ bg, const int* __restrict__ starts,
                  float* __restrict__ psum, float* __restrict__ pmax) {
    const int g  = blockIdx.x / PCH;
    const int ch = blockIdx.x % PCH;
    const int c  = threadIdx.x;
    const int s0 = starts[g], s1 = starts[g + 1];
    const int total = s1 - s0;
    const int len = (total + PCH - 1) / PCH;
    const int n0 = s0 + ch * len;
    const int n1 = min(n0 + len, s1);
    const float w = wg[c];
    const float b = bg[0];
    __shared__ float red[2];
    float sum = 0.f, mx = -__builtin_inff();
    for (int n = n0; n < n1; ++n) {
        const float xv = x[n * 128 + c];
        float p = xv * w;
        #pragma unroll
        for (int o = 32; o; o >>= 1) p += __shfl_xor(p, o);
        if ((c & 63) == 0) red[c >> 6] = p;
        __syncthreads();
        const float dot = red[0] + red[1];
        __syncthreads();
        const float score = 1.f / (1.f + __expf(-(dot + b)));
        sum += score * xv;
        mx = fmaxf(mx, xv);
    }
    psum[blockIdx.x * 128 + c] = sum;
    pmax[blockIdx.x * 128 + c] = mx;
}

__global__ __launch_bounds__(128)
void pool_final(const float* __restrict__ psum, const float* __restrict__ pmax,
                float* __restrict__ out) {
    const int g = blockIdx.x, c = threadIdx.x;
    float s = 0.f, m = -__builtin_inff();
    #pragma unroll
    for (int ch = 0; ch < PCH; ++ch) {
        s += psum[(g * PCH + ch) * 128 + c];
        m = fmaxf(m, pmax[(g * PCH + ch) * 128 + c]);
    }
    out[g * 256 + c] = s;
    out[g * 256 + 128 + c] = m;
}

// ---------------------------------------------------------------- launch
extern "C" void kernel_launch(void* const* d_in, const int* in_sizes, int n_in,
                              void* d_out, int out_size, void* d_ws, size_t ws_size,
                              hipStream_t stream) {
    const float* x     = (const float*)d_in[0];
    const int*   ei    = (const int*)d_in[1];
    const int*   batch = (const int*)d_in[2];
    const float* Wq = (const float*)d_in[3];
    const float* bq = (const float*)d_in[4];
    const float* Wk = (const float*)d_in[5];
    const float* bk = (const float*)d_in[6];
    const float* Wv = (const float*)d_in[7];
    const float* bv = (const float*)d_in[8];
    const float* Ws = (const float*)d_in[9];
    const float* bs = (const float*)d_in[10];
    const float* wg = (const float*)d_in[11];
    const float* bg = (const float*)d_in[12];
    float* out = (float*)d_out;

    char* w = (char*)d_ws;
    float* qb    = (float*)w; w += (size_t)NN * 128 * 4;
    float* kb    = (float*)w; w += (size_t)NN * 128 * 4;
    float* vb    = (float*)w; w += (size_t)NN * 128 * 4;
    float* bufA  = (float*)w; w += (size_t)NN * 128 * 4;
    float* bufB  = (float*)w; w += (size_t)NN * 128 * 4;
    float* psum  = (float*)w; w += (size_t)GG * PCH * 128 * 4;
    float* pmax  = (float*)w; w += (size_t)GG * PCH * 128 * 4;
    int* counts  = (int*)w;   w += (size_t)NN * 4;
    int* offsets = (int*)w;   w += (size_t)(NN + 1) * 4;
    int* csrc    = (int*)w;   w += (size_t)EE * 4;
    int* starts  = (int*)w;   w += (size_t)(GG + 1) * 4;

    const int* srcI = ei;
    const int* dstI = ei + EE;

    // CSR over dst (reused by all 3 layers)
    hipMemsetAsync(counts, 0, (size_t)NN * 4, stream);
    hist_kernel<<<(EE + 255) / 256, 256, 0, stream>>>(dstI, counts);
    scan_kernel<<<1, 1024, 0, stream>>>(counts, offsets);
    hipMemsetAsync(counts, 0, (size_t)NN * 4, stream);  // reuse as cursor
    scatter_kernel<<<(EE + 255) / 256, 256, 0, stream>>>(srcI, dstI, offsets, counts, csrc);
    starts_kernel<<<(NN + 256) / 256, 256, 0, stream>>>(batch, starts);

    const float* xin = x;
    float* bufs[2] = {bufA, bufB};
    const int nodeBlocks = (NN + 31) / 32;  // 1563
    for (int l = 0; l < 3; ++l) {
        float* xs = bufs[l & 1];
        gemm_qkvs<<<dim3(nodeBlocks, 4), 256, 0, stream>>>(
            xin,
            Wq + (size_t)l * 16384, bq + (size_t)l * 128,
            Wk + (size_t)l * 16384, bk + (size_t)l * 128,
            Wv + (size_t)l * 16384, bv + (size_t)l * 128,
            Ws + (size_t)l * 16384, bs + (size_t)l * 128,
            qb, kb, vb, xs);
        attn_kernel<<<nodeBlocks, 256, 0, stream>>>(qb, kb, vb, xs, offsets, csrc);
        xin = xs;
    }

    pool_partial<<<GG * PCH, 128, 0, stream>>>(xin, wg, bg, starts, psum, pmax);
    pool_final<<<GG, 128, 0, stream>>>(psum, pmax, out);
}

// Round 5
// 919.114 us; speedup vs baseline: 1.2411x; 1.0585x over previous
//
#include <hip/hip_runtime.h>
#include <hip/hip_bf16.h>

#define NN 50000
#define EE 800000
#define GG 64
#define PCH 16   // pooling chunks per graph
// D=128, H=8, C=16, L=3

// bf16 helpers (bit-pattern based, no dependence on __hip_bfloat16 internals)
union BFU { __hip_bfloat16 h; unsigned short u; };
__device__ __forceinline__ unsigned short f2bf(float f) {
    BFU b; b.h = __float2bfloat16(f); return b.u;
}
#define B2F_LO(u) __uint_as_float((u) << 16)
#define B2F_HI(u) __uint_as_float((u) & 0xffff0000u)

// ---------------------------------------------------------------- CSR build
__global__ __launch_bounds__(256) void hist_kernel(const int* __restrict__ dst,
                                                   int* __restrict__ counts) {
    int e = blockIdx.x * 256 + threadIdx.x;
    if (e < EE) atomicAdd(&counts[dst[e]], 1);
}

__global__ __launch_bounds__(1024) void scan_kernel(const int* __restrict__ counts,
                                                    int* __restrict__ offsets) {
    __shared__ int part[1024];
    const int t = threadIdx.x;
    const int CH = (NN + 1023) / 1024;  // 49
    const int st = t * CH;
    int s = 0;
    for (int i = 0; i < CH; ++i) {
        int idx = st + i;
        if (idx < NN) s += counts[idx];
    }
    part[t] = s;
    __syncthreads();
    for (int off = 1; off < 1024; off <<= 1) {
        int val = (t >= off) ? part[t - off] : 0;
        __syncthreads();
        part[t] += val;
        __syncthreads();
    }
    int run = (t == 0) ? 0 : part[t - 1];
    for (int i = 0; i < CH; ++i) {
        int idx = st + i;
        if (idx < NN) { offsets[idx] = run; run += counts[idx]; }
    }
    if (t == 1023) offsets[NN] = part[1023];
}

__global__ __launch_bounds__(256) void scatter_kernel(const int* __restrict__ src,
                                                      const int* __restrict__ dst,
                                                      const int* __restrict__ offs,
                                                      int* __restrict__ cursor,
                                                      int* __restrict__ csrc) {
    int e = blockIdx.x * 256 + threadIdx.x;
    if (e < EE) {
        int dn = dst[e];
        int p = atomicAdd(&cursor[dn], 1);
        csrc[offs[dn] + p] = src[e];
    }
}

__global__ __launch_bounds__(256) void starts_kernel(const int* __restrict__ batch,
                                                     int* __restrict__ starts) {
    int i = blockIdx.x * 256 + threadIdx.x;
    if (i > NN) return;
    int b  = (i < NN) ? batch[i] : GG;
    int bp = (i == 0) ? -1 : batch[i - 1];
    for (int g = bp + 1; g <= b && g <= GG; ++g) starts[g] = i;
}

// ---------------------------------------------------------------- fused QKV+skip GEMM
// One block = 32-node tile; x staged in LDS ONCE, then m=0..3 loops over the
// 4 weight matrices. q,xs written fp32; k,v written packed bf16 interleaved.
// Layout (ushort units): kvb[node*256 + h*32 + 0..15] = k head h,
//                        kvb[node*256 + h*32 + 16..31] = v head h.
__global__ __launch_bounds__(256)
void gemm_fused(const float* __restrict__ xin,
                const float* __restrict__ Wq, const float* __restrict__ bq,
                const float* __restrict__ Wk, const float* __restrict__ bk,
                const float* __restrict__ Wv, const float* __restrict__ bv,
                const float* __restrict__ Ws, const float* __restrict__ bs,
                float* __restrict__ q, unsigned short* __restrict__ kvb,
                float* __restrict__ xs) {
    __shared__ float wl[32 * 128];
    __shared__ float xl[32 * 128];
    const int t = threadIdx.x;
    const int n0 = blockIdx.x * 32;
    float4* xl4 = (float4*)xl;
    const float4* X4 = (const float4*)xin;
    for (int i = t; i < 1024; i += 256) {          // 32 rows x 32 float4
        int node = n0 + (i >> 5);
        float4 val = make_float4(0.f, 0.f, 0.f, 0.f);
        if (node < NN) val = X4[node * 32 + (i & 31)];
        xl4[i] = val;
    }
    const int cg = t & 31;   // cols cg*4..cg*4+3
    const int ng = t >> 5;   // nodes ng*4..ng*4+3
    float4* wl4 = (float4*)wl;

    for (int m = 0; m < 4; ++m) {
        const float* W; const float* b;
        switch (m) {
            case 0:  W = Wq; b = bq; break;
            case 1:  W = Wk; b = bk; break;
            case 2:  W = Wv; b = bv; break;
            default: W = Ws; b = bs; break;
        }
        const float4* W4 = (const float4*)W;
        float4 acc[4] = {};
        for (int kc = 0; kc < 4; ++kc) {
            __syncthreads();
            for (int i = t; i < 1024; i += 256) wl4[i] = W4[kc * 1024 + i];
            __syncthreads();
            #pragma unroll
            for (int k0 = 0; k0 < 32; k0 += 4) {
                float4 w0 = *(const float4*)&wl[(k0 + 0) * 128 + cg * 4];
                float4 w1 = *(const float4*)&wl[(k0 + 1) * 128 + cg * 4];
                float4 w2 = *(const float4*)&wl[(k0 + 2) * 128 + cg * 4];
                float4 w3 = *(const float4*)&wl[(k0 + 3) * 128 + cg * 4];
                #pragma unroll
                for (int r = 0; r < 4; ++r) {
                    const float4 xv = *(const float4*)&xl[(ng * 4 + r) * 128 + kc * 32 + k0];
                    acc[r].x += xv.x * w0.x + xv.y * w1.x + xv.z * w2.x + xv.w * w3.x;
                    acc[r].y += xv.x * w0.y + xv.y * w1.y + xv.z * w2.y + xv.w * w3.y;
                    acc[r].z += xv.x * w0.z + xv.y * w1.z + xv.z * w2.z + xv.w * w3.z;
                    acc[r].w += xv.x * w0.w + xv.y * w1.w + xv.z * w2.w + xv.w * w3.w;
                }
            }
        }
        const float4 bb = *(const float4*)&b[cg * 4];
        if (m == 0 || m == 3) {
            float* out = (m == 0) ? q : xs;
            #pragma unroll
            for (int r = 0; r < 4; ++r) {
                int node = n0 + ng * 4 + r;
                if (node < NN) {
                    float4 o = make_float4(acc[r].x + bb.x, acc[r].y + bb.y,
                                           acc[r].z + bb.z, acc[r].w + bb.w);
                    *((float4*)&out[node * 128 + cg * 4]) = o;
                }
            }
        } else {
            const int koff = (m == 1) ? 0 : 16;       // k at +0, v at +16 (ushorts)
            const int c0 = cg * 4;
            const int h = c0 >> 4, i4 = c0 & 15;
            #pragma unroll
            for (int r = 0; r < 4; ++r) {
                int node = n0 + ng * 4 + r;
                if (node < NN) {
                    ushort4 s4;
                    s4.x = f2bf(acc[r].x + bb.x);
                    s4.y = f2bf(acc[r].y + bb.y);
                    s4.z = f2bf(acc[r].z + bb.z);
                    s4.w = f2bf(acc[r].w + bb.w);
                    *(ushort4*)(kvb + (size_t)node * 256 + h * 32 + koff + i4) = s4;
                }
            }
        }
    }
}

// ---------------------------------------------------------------- attention (CSR, online softmax)
// thread = (node, head); 8 lanes cover one node's heads; per edge each lane
// reads its 64B contiguous chunk of the 512B kv row (k 32B + v 32B bf16).
__global__ __launch_bounds__(256)
void attn_kernel(const float* __restrict__ q, const uint4* __restrict__ kv4,
                 float* __restrict__ xio,
                 const int* __restrict__ offs, const int* __restrict__ csrc) {
    const int t = threadIdx.x;
    const int h = t & 7;
    const int n = blockIdx.x * 32 + (t >> 3);
    if (n >= NN) return;
    const float4* qp = (const float4*)(q + n * 128 + h * 16);
    const float4 q0 = qp[0], q1 = qp[1], q2 = qp[2], q3 = qp[3];
    float m = -__builtin_inff();
    float d = 0.f;
    float4 a0 = {}, a1 = {}, a2 = {}, a3 = {};
    const int e0 = offs[n], e1 = offs[n + 1];
    for (int e = e0; e < e1; ++e) {
        const int s = csrc[e];
        const uint4* kvp = kv4 + (size_t)s * 32 + h * 4;   // 512B row, 64B per head
        const uint4 ka = kvp[0], kb = kvp[1];              // k: 16 bf16
        float dot =
            q0.x * B2F_LO(ka.x) + q0.y * B2F_HI(ka.x) + q0.z * B2F_LO(ka.y) + q0.w * B2F_HI(ka.y)
          + q1.x * B2F_LO(ka.z) + q1.y * B2F_HI(ka.z) + q1.z * B2F_LO(ka.w) + q1.w * B2F_HI(ka.w)
          + q2.x * B2F_LO(kb.x) + q2.y * B2F_HI(kb.x) + q2.z * B2F_LO(kb.y) + q2.w * B2F_HI(kb.y)
          + q3.x * B2F_LO(kb.z) + q3.y * B2F_HI(kb.z) + q3.z * B2F_LO(kb.w) + q3.w * B2F_HI(kb.w);
        const float alpha = dot * 0.25f;                   // / sqrt(C=16)
        const float nm = fmaxf(m, alpha);
        const float scale = __expf(m - nm);                // 0 on first edge
        const float p = __expf(alpha - nm);
        d = d * scale + p;
        const uint4 va = kvp[2], vb = kvp[3];              // v: 16 bf16
        a0.x = a0.x * scale + p * B2F_LO(va.x); a0.y = a0.y * scale + p * B2F_HI(va.x);
        a0.z = a0.z * scale + p * B2F_LO(va.y); a0.w = a0.w * scale + p * B2F_HI(va.y);
        a1.x = a1.x * scale + p * B2F_LO(va.z); a1.y = a1.y * scale + p * B2F_HI(va.z);
        a1.z = a1.z * scale + p * B2F_LO(va.w); a1.w = a1.w * scale + p * B2F_HI(va.w);
        a2.x = a2.x * scale + p * B2F_LO(vb.x); a2.y = a2.y * scale + p * B2F_HI(vb.x);
        a2.z = a2.z * scale + p * B2F_LO(vb.y); a2.w = a2.w * scale + p * B2F_HI(vb.y);
        a3.x = a3.x * scale + p * B2F_LO(vb.z); a3.y = a3.y * scale + p * B2F_HI(vb.z);
        a3.z = a3.z * scale + p * B2F_LO(vb.w); a3.w = a3.w * scale + p * B2F_HI(vb.w);
        m = nm;
    }
    const float inv = 1.f / (d + 1e-16f);
    float4* op = (float4*)(xio + n * 128 + h * 16);
    float4 o0 = op[0], o1 = op[1], o2 = op[2], o3 = op[3];
    o0.x += a0.x * inv; o0.y += a0.y * inv; o0.z += a0.z * inv; o0.w += a0.w * inv;
    o1.x += a1.x * inv; o1.y += a1.y * inv; o1.z += a1.z * inv; o1.w += a1.w * inv;
    o2.x += a2.x * inv; o2.y += a2.y * inv; o2.z += a2.z * inv; o2.w += a2.w * inv;
    o3.x += a3.x * inv; o3.y += a3.y * inv; o3.z += a3.z * inv; o3.w += a3.w * inv;
    op[0] = o0; op[1] = o1; op[2] = o2; op[3] = o3;
}

// ---------------------------------------------------------------- readout (2-phase, fused gate)
__global__ __launch_bounds__(128)
void pool_partial(const float* __restrict__ x, const float* __restrict__ wg,
                  const float* __restrict__ bg, const int* __restrict__ starts,
                  float* __restrict__ psum, float* __restrict__ pmax) {
    const int g  = blockIdx.x / PCH;
    const int ch = blockIdx.x % PCH;
    const int c  = threadIdx.x;
    const int s0 = starts[g], s1 = starts[g + 1];
    const int total = s1 - s0;
    const int len = (total + PCH - 1) / PCH;
    const int n0 = s0 + ch * len;
    const int n1 = min(n0 + len, s1);
    const float w = wg[c];
    const float b = bg[0];
    __shared__ float red[2];
    float sum = 0.f, mx = -__builtin_inff();
    for (int n = n0; n < n1; ++n) {
        const float xv = x[n * 128 + c];
        float p = xv * w;
        #pragma unroll
        for (int o = 32; o; o >>= 1) p += __shfl_xor(p, o);
        if ((c & 63) == 0) red[c >> 6] = p;
        __syncthreads();
        const float dot = red[0] + red[1];
        __syncthreads();
        const float score = 1.f / (1.f + __expf(-(dot + b)));
        sum += score * xv;
        mx = fmaxf(mx, xv);
    }
    psum[blockIdx.x * 128 + c] = sum;
    pmax[blockIdx.x * 128 + c] = mx;
}

__global__ __launch_bounds__(128)
void pool_final(const float* __restrict__ psum, const float* __restrict__ pmax,
                float* __restrict__ out) {
    const int g = blockIdx.x, c = threadIdx.x;
    float s = 0.f, m = -__builtin_inff();
    #pragma unroll
    for (int ch = 0; ch < PCH; ++ch) {
        s += psum[(g * PCH + ch) * 128 + c];
        m = fmaxf(m, pmax[(g * PCH + ch) * 128 + c]);
    }
    out[g * 256 + c] = s;
    out[g * 256 + 128 + c] = m;
}

// ---------------------------------------------------------------- launch
extern "C" void kernel_launch(void* const* d_in, const int* in_sizes, int n_in,
                              void* d_out, int out_size, void* d_ws, size_t ws_size,
                              hipStream_t stream) {
    const float* x     = (const float*)d_in[0];
    const int*   ei    = (const int*)d_in[1];
    const int*   batch = (const int*)d_in[2];
    const float* Wq = (const float*)d_in[3];
    const float* bq = (const float*)d_in[4];
    const float* Wk = (const float*)d_in[5];
    const float* bk = (const float*)d_in[6];
    const float* Wv = (const float*)d_in[7];
    const float* bv = (const float*)d_in[8];
    const float* Ws = (const float*)d_in[9];
    const float* bs = (const float*)d_in[10];
    const float* wg = (const float*)d_in[11];
    const float* bg = (const float*)d_in[12];
    float* out = (float*)d_out;

    char* w = (char*)d_ws;
    float* qb            = (float*)w;          w += (size_t)NN * 128 * 4;
    unsigned short* kvb  = (unsigned short*)w; w += (size_t)NN * 256 * 2;
    float* bufA          = (float*)w;          w += (size_t)NN * 128 * 4;
    float* bufB          = (float*)w;          w += (size_t)NN * 128 * 4;
    float* psum          = (float*)w;          w += (size_t)GG * PCH * 128 * 4;
    float* pmax          = (float*)w;          w += (size_t)GG * PCH * 128 * 4;
    int* counts          = (int*)w;            w += (size_t)NN * 4;
    int* offsets         = (int*)w;            w += (size_t)(NN + 1) * 4;
    int* csrc            = (int*)w;            w += (size_t)EE * 4;
    int* starts          = (int*)w;            w += (size_t)(GG + 1) * 4;

    const int* srcI = ei;
    const int* dstI = ei + EE;

    // CSR over dst (reused by all 3 layers)
    hipMemsetAsync(counts, 0, (size_t)NN * 4, stream);
    hist_kernel<<<(EE + 255) / 256, 256, 0, stream>>>(dstI, counts);
    scan_kernel<<<1, 1024, 0, stream>>>(counts, offsets);
    hipMemsetAsync(counts, 0, (size_t)NN * 4, stream);  // reuse as cursor
    scatter_kernel<<<(EE + 255) / 256, 256, 0, stream>>>(srcI, dstI, offsets, counts, csrc);
    starts_kernel<<<(NN + 256) / 256, 256, 0, stream>>>(batch, starts);

    const float* xin = x;
    float* bufs[2] = {bufA, bufB};
    const int nodeBlocks = (NN + 31) / 32;  // 1563
    for (int l = 0; l < 3; ++l) {
        float* xs = bufs[l & 1];
        gemm_fused<<<nodeBlocks, 256, 0, stream>>>(
            xin,
            Wq + (size_t)l * 16384, bq + (size_t)l * 128,
            Wk + (size_t)l * 16384, bk + (size_t)l * 128,
            Wv + (size_t)l * 16384, bv + (size_t)l * 128,
            Ws + (size_t)l * 16384, bs + (size_t)l * 128,
            qb, kvb, xs);
        attn_kernel<<<nodeBlocks, 256, 0, stream>>>(qb, (const uint4*)kvb, xs, offsets, csrc);
        xin = xs;
    }

    pool_partial<<<GG * PCH, 128, 0, stream>>>(xin, wg, bg, starts, psum, pmax);
    pool_final<<<GG, 128, 0, stream>>>(psum, pmax, out);
}

// Round 6
// 621.332 us; speedup vs baseline: 1.8360x; 1.4793x over previous
//
#include <hip/hip_runtime.h>
#include <hip/hip_bf16.h>

#define NN 50000
#define EE 800000
#define GG 64
#define PCH 16   // pooling chunks per graph
// D=128, H=8, C=16, L=3

typedef __attribute__((ext_vector_type(8)))  short          s16x8;
typedef __attribute__((ext_vector_type(8)))  unsigned short u16x8;
typedef __attribute__((ext_vector_type(16))) float          f32x16;

// bf16 helpers (bit-pattern based)
union BFU { __hip_bfloat16 h; unsigned short u; };
__device__ __forceinline__ unsigned short f2bf(float f) {
    BFU b; b.h = __float2bfloat16(f); return b.u;
}
#define B2F_LO(u) __uint_as_float((u) << 16)
#define B2F_HI(u) __uint_as_float((u) & 0xffff0000u)
#define BF2F(us)  __uint_as_float(((unsigned)(us)) << 16)

// ---------------------------------------------------------------- CSR build
__global__ __launch_bounds__(256) void hist_kernel(const int* __restrict__ dst,
                                                   int* __restrict__ counts) {
    int e = blockIdx.x * 256 + threadIdx.x;
    if (e < EE) atomicAdd(&counts[dst[e]], 1);
}

__global__ __launch_bounds__(1024) void scan_kernel(const int* __restrict__ counts,
                                                    int* __restrict__ offsets) {
    __shared__ int part[1024];
    const int t = threadIdx.x;
    const int CH = (NN + 1023) / 1024;  // 49
    const int st = t * CH;
    int s = 0;
    for (int i = 0; i < CH; ++i) {
        int idx = st + i;
        if (idx < NN) s += counts[idx];
    }
    part[t] = s;
    __syncthreads();
    for (int off = 1; off < 1024; off <<= 1) {
        int val = (t >= off) ? part[t - off] : 0;
        __syncthreads();
        part[t] += val;
        __syncthreads();
    }
    int run = (t == 0) ? 0 : part[t - 1];
    for (int i = 0; i < CH; ++i) {
        int idx = st + i;
        if (idx < NN) { offsets[idx] = run; run += counts[idx]; }
    }
    if (t == 1023) offsets[NN] = part[1023];
}

__global__ __launch_bounds__(256) void scatter_kernel(const int* __restrict__ src,
                                                      const int* __restrict__ dst,
                                                      const int* __restrict__ offs,
                                                      int* __restrict__ cursor,
                                                      int* __restrict__ csrc) {
    int e = blockIdx.x * 256 + threadIdx.x;
    if (e < EE) {
        int dn = dst[e];
        int p = atomicAdd(&cursor[dn], 1);
        csrc[offs[dn] + p] = src[e];
    }
}

__global__ __launch_bounds__(256) void starts_kernel(const int* __restrict__ batch,
                                                     int* __restrict__ starts) {
    int i = blockIdx.x * 256 + threadIdx.x;
    if (i > NN) return;
    int b  = (i < NN) ? batch[i] : GG;
    int bp = (i == 0) ? -1 : batch[i - 1];
    for (int g = bp + 1; g <= b && g <= GG; ++g) starts[g] = i;
}

// ---------------------------------------------------------------- weight prep
// W[l][k][c] fp32 -> transposed split-bf16: wtb[mat][c][k], mat = l*4+m.
// hi = bf16(w), lo = bf16(w - hi): 3-term MFMA reconstructs ~fp32 accuracy.
__global__ __launch_bounds__(256)
void prep_weights(const float* __restrict__ Wq, const float* __restrict__ Wk,
                  const float* __restrict__ Wv, const float* __restrict__ Ws,
                  unsigned short* __restrict__ wtbh, unsigned short* __restrict__ wtbl) {
    const int mat = blockIdx.x;           // 0..11
    const int l = mat >> 2, m = mat & 3;
    const float* W;
    switch (m) {
        case 0:  W = Wq; break;
        case 1:  W = Wk; break;
        case 2:  W = Wv; break;
        default: W = Ws; break;
    }
    W += (size_t)l * 16384;
    const int t = threadIdx.x;
    const int col = blockIdx.y * 16 + (t >> 4);
    const int kb  = (t & 15) * 8;
    u16x8 hi, lo;
    #pragma unroll
    for (int j = 0; j < 8; ++j) {
        float w = W[(kb + j) * 128 + col];
        unsigned short uh = f2bf(w);
        hi[j] = uh;
        lo[j] = f2bf(w - BF2F(uh));
    }
    const size_t o = (size_t)mat * 16384 + col * 128 + kb;
    *(u16x8*)(wtbh + o) = hi;
    *(u16x8*)(wtbl + o) = lo;
}

// ---------------------------------------------------------------- MFMA GEMM (split-bf16)
// Block: 64 nodes x 128 cols; 4 waves, each 32 nodes x 64 cols via
// mfma_f32_32x32x16_bf16. LDS: xl = x hi|lo bf16 (32KB), wsm = W tile (32KB),
// both XOR-swizzled (chunk ^= row&7) to kill the stride-256B bank conflict.
// acc = xh*Wh + xl*Wh + xh*Wl  (fp32-quality).
// Outputs: m=0 -> q fp32; m=3 -> xs fp32; m=1,2 -> packed bf16 kv rows:
//   kvb[node*256 + h*32 + 0..15]=k, +16..31=v.
__global__ __launch_bounds__(256, 2)
void gemm_mfma(const float* __restrict__ xin,
               const unsigned short* __restrict__ wHg,   // + l*4*16384
               const unsigned short* __restrict__ wLg,
               const float* __restrict__ bq, const float* __restrict__ bk,
               const float* __restrict__ bv, const float* __restrict__ bs,
               float* __restrict__ q, unsigned short* __restrict__ kvb,
               float* __restrict__ xs) {
    __shared__ unsigned short xl[16384];   // [0..8191]=hi, [8192..]=lo
    __shared__ unsigned short wsm[16384];
    const int t = threadIdx.x;
    const int n0 = blockIdx.x * 64;

    // ---- stage x (fp32 -> split bf16, swizzled) ----
    const float4* X4 = (const float4*)xin;
    for (int i = t; i < 1024; i += 256) {            // 64 rows x 16 chunks
        const int row = i >> 4, ch = i & 15;
        const int node = n0 + row;
        float4 fa = make_float4(0.f, 0.f, 0.f, 0.f);
        float4 fb = make_float4(0.f, 0.f, 0.f, 0.f);
        if (node < NN) { fa = X4[node * 32 + ch * 2]; fb = X4[node * 32 + ch * 2 + 1]; }
        const float fv[8] = {fa.x, fa.y, fa.z, fa.w, fb.x, fb.y, fb.z, fb.w};
        u16x8 hi, lo;
        #pragma unroll
        for (int j = 0; j < 8; ++j) {
            unsigned short uh = f2bf(fv[j]);
            hi[j] = uh;
            lo[j] = f2bf(fv[j] - BF2F(uh));
        }
        const int base = row * 128 + (ch ^ (row & 7)) * 8;
        *(u16x8*)&xl[base] = hi;
        *(u16x8*)&xl[8192 + base] = lo;
    }
    __syncthreads();

    // ---- per-wave tile & A-fragments (held in regs for all 4 matrices) ----
    const int lane = t & 63, wid = t >> 6;
    const int r = lane & 31, g = lane >> 5;
    const int nt = (wid & 1) * 32;        // node offset in tile
    const int cb = (wid >> 1) * 64;       // col base
    s16x8 ah[8], al[8];
    {
        const int row = nt + r;
        const int s = row & 7;
        const int rb = row * 128;
        #pragma unroll
        for (int kc = 0; kc < 8; ++kc) {
            const int idx = rb + (((kc << 1) | g) ^ s) * 8;
            ah[kc] = *(const s16x8*)&xl[idx];
            al[kc] = *(const s16x8*)&xl[8192 + idx];
        }
    }
    const int col0 = cb + r, col1 = cb + 32 + r;
    const int wb0 = col0 * 128, ws0 = col0 & 7;
    const int wb1 = col1 * 128, ws1 = col1 & 7;

    for (int m = 0; m < 4; ++m) {
        f32x16 acc0, acc1;
        #pragma unroll
        for (int j = 0; j < 16; ++j) { acc0[j] = 0.f; acc1[j] = 0.f; }

        #pragma unroll
        for (int part = 0; part < 2; ++part) {
            __syncthreads();
            const u16x8* Wg = (const u16x8*)((part == 0 ? wHg : wLg) + m * 16384);
            for (int i = t; i < 2048; i += 256) {    // 128 rows x 16 chunks
                const int row = i >> 4, ch = i & 15;
                *(u16x8*)&wsm[row * 128 + (ch ^ (row & 7)) * 8] = Wg[i];
            }
            __syncthreads();
            #pragma unroll
            for (int kc = 0; kc < 8; ++kc) {
                const s16x8 b0 = *(const s16x8*)&wsm[wb0 + (((kc << 1) | g) ^ ws0) * 8];
                const s16x8 b1 = *(const s16x8*)&wsm[wb1 + (((kc << 1) | g) ^ ws1) * 8];
                acc0 = __builtin_amdgcn_mfma_f32_32x32x16_bf16(ah[kc], b0, acc0, 0, 0, 0);
                acc1 = __builtin_amdgcn_mfma_f32_32x32x16_bf16(ah[kc], b1, acc1, 0, 0, 0);
                if (part == 0) {
                    acc0 = __builtin_amdgcn_mfma_f32_32x32x16_bf16(al[kc], b0, acc0, 0, 0, 0);
                    acc1 = __builtin_amdgcn_mfma_f32_32x32x16_bf16(al[kc], b1, acc1, 0, 0, 0);
                }
            }
        }

        // ---- epilogue ----
        const float* bp;
        switch (m) {
            case 0:  bp = bq; break;
            case 1:  bp = bk; break;
            case 2:  bp = bv; break;
            default: bp = bs; break;
        }
        const float b0 = bp[col0], b1 = bp[col1];
        if (m == 0 || m == 3) {
            float* outp = (m == 0) ? q : xs;
            #pragma unroll
            for (int reg = 0; reg < 16; ++reg) {
                const int node = n0 + nt + (reg & 3) + 8 * (reg >> 2) + 4 * g;
                if (node < NN) {
                    outp[node * 128 + col0] = acc0[reg] + b0;
                    outp[node * 128 + col1] = acc1[reg] + b1;
                }
            }
        } else {
            const int koff = (m == 1) ? 0 : 16;      // k at +0, v at +16 (ushorts)
            const int o0 = (col0 >> 4) * 32 + koff + (col0 & 15);
            const int o1 = (col1 >> 4) * 32 + koff + (col1 & 15);
            #pragma unroll
            for (int reg = 0; reg < 16; ++reg) {
                const int node = n0 + nt + (reg & 3) + 8 * (reg >> 2) + 4 * g;
                if (node < NN) {
                    kvb[(size_t)node * 256 + o0] = f2bf(acc0[reg] + b0);
                    kvb[(size_t)node * 256 + o1] = f2bf(acc1[reg] + b1);
                }
            }
        }
    }
}

// ---------------------------------------------------------------- attention (CSR, online softmax)
// thread = (node, head); 8 lanes cover one node's heads; per edge each lane
// reads its 64B contiguous chunk of the 512B kv row (k 32B + v 32B bf16).
__global__ __launch_bounds__(256)
void attn_kernel(const float* __restrict__ q, const uint4* __restrict__ kv4,
                 float* __restrict__ xio,
                 const int* __restrict__ offs, const int* __restrict__ csrc) {
    const int t = threadIdx.x;
    const int h = t & 7;
    const int n = blockIdx.x * 32 + (t >> 3);
    if (n >= NN) return;
    const float4* qp = (const float4*)(q + n * 128 + h * 16);
    const float4 q0 = qp[0], q1 = qp[1], q2 = qp[2], q3 = qp[3];
    float m = -__builtin_inff();
    float d = 0.f;
    float4 a0 = {}, a1 = {}, a2 = {}, a3 = {};
    const int e0 = offs[n], e1 = offs[n + 1];
    for (int e = e0; e < e1; ++e) {
        const int s = csrc[e];
        const uint4* kvp = kv4 + (size_t)s * 32 + h * 4;   // 512B row, 64B per head
        const uint4 ka = kvp[0], kb = kvp[1];              // k: 16 bf16
        float dot =
            q0.x * B2F_LO(ka.x) + q0.y * B2F_HI(ka.x) + q0.z * B2F_LO(ka.y) + q0.w * B2F_HI(ka.y)
          + q1.x * B2F_LO(ka.z) + q1.y * B2F_HI(ka.z) + q1.z * B2F_LO(ka.w) + q1.w * B2F_HI(ka.w)
          + q2.x * B2F_LO(kb.x) + q2.y * B2F_HI(kb.x) + q2.z * B2F_LO(kb.y) + q2.w * B2F_HI(kb.y)
          + q3.x * B2F_LO(kb.z) + q3.y * B2F_HI(kb.z) + q3.z * B2F_LO(kb.w) + q3.w * B2F_HI(kb.w);
        const float alpha = dot * 0.25f;                   // / sqrt(C=16)
        const float nm = fmaxf(m, alpha);
        const float scale = __expf(m - nm);                // 0 on first edge
        const float p = __expf(alpha - nm);
        d = d * scale + p;
        const uint4 va = kvp[2], vb = kvp[3];              // v: 16 bf16
        a0.x = a0.x * scale + p * B2F_LO(va.x); a0.y = a0.y * scale + p * B2F_HI(va.x);
        a0.z = a0.z * scale + p * B2F_LO(va.y); a0.w = a0.w * scale + p * B2F_HI(va.y);
        a1.x = a1.x * scale + p * B2F_LO(va.z); a1.y = a1.y * scale + p * B2F_HI(va.z);
        a1.z = a1.z * scale + p * B2F_LO(va.w); a1.w = a1.w * scale + p * B2F_HI(va.w);
        a2.x = a2.x * scale + p * B2F_LO(vb.x); a2.y = a2.y * scale + p * B2F_HI(vb.x);
        a2.z = a2.z * scale + p * B2F_LO(vb.y); a2.w = a2.w * scale + p * B2F_HI(vb.y);
        a3.x = a3.x * scale + p * B2F_LO(vb.z); a3.y = a3.y * scale + p * B2F_HI(vb.z);
        a3.z = a3.z * scale + p * B2F_LO(vb.w); a3.w = a3.w * scale + p * B2F_HI(vb.w);
        m = nm;
    }
    const float inv = 1.f / (d + 1e-16f);
    float4* op = (float4*)(xio + n * 128 + h * 16);
    float4 o0 = op[0], o1 = op[1], o2 = op[2], o3 = op[3];
    o0.x += a0.x * inv; o0.y += a0.y * inv; o0.z += a0.z * inv; o0.w += a0.w * inv;
    o1.x += a1.x * inv; o1.y += a1.y * inv; o1.z += a1.z * inv; o1.w += a1.w * inv;
    o2.x += a2.x * inv; o2.y += a2.y * inv; o2.z += a2.z * inv; o2.w += a2.w * inv;
    o3.x += a3.x * inv; o3.y += a3.y * inv; o3.z += a3.z * inv; o3.w += a3.w * inv;
    op[0] = o0; op[1] = o1; op[2] = o2; op[3] = o3;
}

// ---------------------------------------------------------------- readout (2-phase, fused gate)
__global__ __launch_bounds__(128)
void pool_partial(const float* __restrict__ x, const float* __restrict__ wg,
                  const float* __restrict__ bg, const int* __restrict__ starts,
                  float* __restrict__ psum, float* __restrict__ pmax) {
    const int g  = blockIdx.x / PCH;
    const int ch = blockIdx.x % PCH;
    const int c  = threadIdx.x;
    const int s0 = starts[g], s1 = starts[g + 1];
    const int total = s1 - s0;
    const int len = (total + PCH - 1) / PCH;
    const int n0 = s0 + ch * len;
    const int n1 = min(n0 + len, s1);
    const float w = wg[c];
    const float b = bg[0];
    __shared__ float red[2];
    float sum = 0.f, mx = -__builtin_inff();
    for (int n = n0; n < n1; ++n) {
        const float xv = x[n * 128 + c];
        float p = xv * w;
        #pragma unroll
        for (int o = 32; o; o >>= 1) p += __shfl_xor(p, o);
        if ((c & 63) == 0) red[c >> 6] = p;
        __syncthreads();
        const float dot = red[0] + red[1];
        __syncthreads();
        const float score = 1.f / (1.f + __expf(-(dot + b)));
        sum += score * xv;
        mx = fmaxf(mx, xv);
    }
    psum[blockIdx.x * 128 + c] = sum;
    pmax[blockIdx.x * 128 + c] = mx;
}

__global__ __launch_bounds__(128)
void pool_final(const float* __restrict__ psum, const float* __restrict__ pmax,
                float* __restrict__ out) {
    const int g = blockIdx.x, c = threadIdx.x;
    float s = 0.f, m = -__builtin_inff();
    #pragma unroll
    for (int ch = 0; ch < PCH; ++ch) {
        s += psum[(g * PCH + ch) * 128 + c];
        m = fmaxf(m, pmax[(g * PCH + ch) * 128 + c]);
    }
    out[g * 256 + c] = s;
    out[g * 256 + 128 + c] = m;
}

// ---------------------------------------------------------------- launch
extern "C" void kernel_launch(void* const* d_in, const int* in_sizes, int n_in,
                              void* d_out, int out_size, void* d_ws, size_t ws_size,
                              hipStream_t stream) {
    const float* x     = (const float*)d_in[0];
    const int*   ei    = (const int*)d_in[1];
    const int*   batch = (const int*)d_in[2];
    const float* Wq = (const float*)d_in[3];
    const float* bq = (const float*)d_in[4];
    const float* Wk = (const float*)d_in[5];
    const float* bk = (const float*)d_in[6];
    const float* Wv = (const float*)d_in[7];
    const float* bv = (const float*)d_in[8];
    const float* Ws = (const float*)d_in[9];
    const float* bs = (const float*)d_in[10];
    const float* wg = (const float*)d_in[11];
    const float* bg = (const float*)d_in[12];
    float* out = (float*)d_out;

    char* w = (char*)d_ws;
    float* qb            = (float*)w;          w += (size_t)NN * 128 * 4;
    unsigned short* kvb  = (unsigned short*)w; w += (size_t)NN * 256 * 2;
    float* bufA          = (float*)w;          w += (size_t)NN * 128 * 4;
    float* bufB          = (float*)w;          w += (size_t)NN * 128 * 4;
    float* psum          = (float*)w;          w += (size_t)GG * PCH * 128 * 4;
    float* pmax          = (float*)w;          w += (size_t)GG * PCH * 128 * 4;
    unsigned short* wtbh = (unsigned short*)w; w += (size_t)12 * 16384 * 2;
    unsigned short* wtbl = (unsigned short*)w; w += (size_t)12 * 16384 * 2;
    int* counts          = (int*)w;            w += (size_t)NN * 4;
    int* offsets         = (int*)w;            w += (size_t)(NN + 1) * 4;
    int* csrc            = (int*)w;            w += (size_t)EE * 4;
    int* starts          = (int*)w;            w += (size_t)(GG + 1) * 4;

    const int* srcI = ei;
    const int* dstI = ei + EE;

    // CSR over dst (reused by all 3 layers) + weight prep
    hipMemsetAsync(counts, 0, (size_t)NN * 4, stream);
    hist_kernel<<<(EE + 255) / 256, 256, 0, stream>>>(dstI, counts);
    scan_kernel<<<1, 1024, 0, stream>>>(counts, offsets);
    hipMemsetAsync(counts, 0, (size_t)NN * 4, stream);  // reuse as cursor
    scatter_kernel<<<(EE + 255) / 256, 256, 0, stream>>>(srcI, dstI, offsets, counts, csrc);
    starts_kernel<<<(NN + 256) / 256, 256, 0, stream>>>(batch, starts);
    prep_weights<<<dim3(12, 8), 256, 0, stream>>>(Wq, Wk, Wv, Ws, wtbh, wtbl);

    const float* xin = x;
    float* bufs[2] = {bufA, bufB};
    const int gemmBlocks = (NN + 63) / 64;   // 782
    const int attnBlocks = (NN + 31) / 32;   // 1563
    for (int l = 0; l < 3; ++l) {
        float* xs = bufs[l & 1];
        gemm_mfma<<<gemmBlocks, 256, 0, stream>>>(
            xin, wtbh + (size_t)l * 4 * 16384, wtbl + (size_t)l * 4 * 16384,
            bq + (size_t)l * 128, bk + (size_t)l * 128,
            bv + (size_t)l * 128, bs + (size_t)l * 128,
            qb, kvb, xs);
        attn_kernel<<<attnBlocks, 256, 0, stream>>>(qb, (const uint4*)kvb, xs, offsets, csrc);
        xin = xs;
    }

    pool_partial<<<GG * PCH, 128, 0, stream>>>(xin, wg, bg, starts, psum, pmax);
    pool_final<<<GG, 128, 0, stream>>>(psum, pmax, out);
}

// Round 7
// 537.109 us; speedup vs baseline: 2.1238x; 1.1568x over previous
//
#include <hip/hip_runtime.h>
#include <hip/hip_bf16.h>

#define NN 50000
#define EE 800000
#define GG 64
#define PCH 16   // pooling chunks per graph
#define SCB ((NN + 255) / 256)   // 196 scan blocks
// D=128, H=8, C=16, L=3

typedef __attribute__((ext_vector_type(8)))  short          s16x8;
typedef __attribute__((ext_vector_type(8)))  unsigned short u16x8;
typedef __attribute__((ext_vector_type(16))) float          f32x16;

// bf16 helpers (bit-pattern based)
union BFU { __hip_bfloat16 h; unsigned short u; };
__device__ __forceinline__ unsigned short f2bf(float f) {
    BFU b; b.h = __float2bfloat16(f); return b.u;
}
#define B2F_LO(u) __uint_as_float((u) << 16)
#define B2F_HI(u) __uint_as_float((u) & 0xffff0000u)
#define BF2F(us)  __uint_as_float(((unsigned)(us)) << 16)

// ---------------------------------------------------------------- CSR build
__global__ __launch_bounds__(256) void hist_kernel(const int* __restrict__ dst,
                                                   int* __restrict__ counts) {
    int e = blockIdx.x * 256 + threadIdx.x;
    if (e < EE) atomicAdd(&counts[dst[e]], 1);
}

// 3-kernel device-wide exclusive scan (replaces the 93us single-block scan:
// that one had stride-49 uncoalesced loads + 0.16% occupancy).
__global__ __launch_bounds__(256)
void block_scan(const int* __restrict__ counts, int* __restrict__ offsets,
                int* __restrict__ bsums) {
    __shared__ int sm[256];
    const int t = threadIdx.x;
    const int i = blockIdx.x * 256 + t;
    const int v = (i < NN) ? counts[i] : 0;
    sm[t] = v;
    __syncthreads();
    for (int off = 1; off < 256; off <<= 1) {
        int val = (t >= off) ? sm[t - off] : 0;
        __syncthreads();
        sm[t] += val;
        __syncthreads();
    }
    if (i < NN) offsets[i] = sm[t] - v;      // exclusive
    if (t == 255) bsums[blockIdx.x] = sm[255];
}

__global__ __launch_bounds__(256)
void scan_sums(int* __restrict__ bsums) {   // in-place -> exclusive block bases
    __shared__ int sm[256];
    const int t = threadIdx.x;
    const int v = (t < SCB) ? bsums[t] : 0;
    sm[t] = v;
    __syncthreads();
    for (int off = 1; off < 256; off <<= 1) {
        int val = (t >= off) ? sm[t - off] : 0;
        __syncthreads();
        sm[t] += val;
        __syncthreads();
    }
    if (t < SCB) bsums[t] = sm[t] - v;       // exclusive base
}

__global__ __launch_bounds__(256)
void add_base(int* __restrict__ offsets, const int* __restrict__ bsums) {
    const int i = blockIdx.x * 256 + threadIdx.x;
    if (i < NN) offsets[i] += bsums[blockIdx.x];
    if (i == 0) offsets[NN] = EE;            // total edges is a constant
}

__global__ __launch_bounds__(256) void scatter_kernel(const int* __restrict__ src,
                                                      const int* __restrict__ dst,
                                                      const int* __restrict__ offs,
                                                      int* __restrict__ cursor,
                                                      int* __restrict__ csrc) {
    int e = blockIdx.x * 256 + threadIdx.x;
    if (e < EE) {
        int dn = dst[e];
        int p = atomicAdd(&cursor[dn], 1);
        csrc[offs[dn] + p] = src[e];
    }
}

__global__ __launch_bounds__(256) void starts_kernel(const int* __restrict__ batch,
                                                     int* __restrict__ starts) {
    int i = blockIdx.x * 256 + threadIdx.x;
    if (i > NN) return;
    int b  = (i < NN) ? batch[i] : GG;
    int bp = (i == 0) ? -1 : batch[i - 1];
    for (int g = bp + 1; g <= b && g <= GG; ++g) starts[g] = i;
}

// ---------------------------------------------------------------- weight prep
// W[l][k][c] fp32 -> transposed split-bf16: wtb[mat][c][k], mat = l*4+m.
__global__ __launch_bounds__(256)
void prep_weights(const float* __restrict__ Wq, const float* __restrict__ Wk,
                  const float* __restrict__ Wv, const float* __restrict__ Ws,
                  unsigned short* __restrict__ wtbh, unsigned short* __restrict__ wtbl) {
    const int mat = blockIdx.x;           // 0..11
    const int l = mat >> 2, m = mat & 3;
    const float* W;
    switch (m) {
        case 0:  W = Wq; break;
        case 1:  W = Wk; break;
        case 2:  W = Wv; break;
        default: W = Ws; break;
    }
    W += (size_t)l * 16384;
    const int t = threadIdx.x;
    const int col = blockIdx.y * 16 + (t >> 4);
    const int kb  = (t & 15) * 8;
    u16x8 hi, lo;
    #pragma unroll
    for (int j = 0; j < 8; ++j) {
        float w = W[(kb + j) * 128 + col];
        unsigned short uh = f2bf(w);
        hi[j] = uh;
        lo[j] = f2bf(w - BF2F(uh));
    }
    const size_t o = (size_t)mat * 16384 + col * 128 + kb;
    *(u16x8*)(wtbh + o) = hi;
    *(u16x8*)(wtbl + o) = lo;
}

// ---------------------------------------------------------------- MFMA GEMM (split-bf16)
__global__ __launch_bounds__(256, 2)
void gemm_mfma(const float* __restrict__ xin,
               const unsigned short* __restrict__ wHg,   // + l*4*16384
               const unsigned short* __restrict__ wLg,
               const float* __restrict__ bq, const float* __restrict__ bk,
               const float* __restrict__ bv, const float* __restrict__ bs,
               float* __restrict__ q, unsigned short* __restrict__ kvb,
               float* __restrict__ xs) {
    __shared__ unsigned short xl[16384];   // [0..8191]=hi, [8192..]=lo
    __shared__ unsigned short wsm[16384];
    const int t = threadIdx.x;
    const int n0 = blockIdx.x * 64;

    // ---- stage x (fp32 -> split bf16, swizzled) ----
    const float4* X4 = (const float4*)xin;
    for (int i = t; i < 1024; i += 256) {            // 64 rows x 16 chunks
        const int row = i >> 4, ch = i & 15;
        const int node = n0 + row;
        float4 fa = make_float4(0.f, 0.f, 0.f, 0.f);
        float4 fb = make_float4(0.f, 0.f, 0.f, 0.f);
        if (node < NN) { fa = X4[node * 32 + ch * 2]; fb = X4[node * 32 + ch * 2 + 1]; }
        const float fv[8] = {fa.x, fa.y, fa.z, fa.w, fb.x, fb.y, fb.z, fb.w};
        u16x8 hi, lo;
        #pragma unroll
        for (int j = 0; j < 8; ++j) {
            unsigned short uh = f2bf(fv[j]);
            hi[j] = uh;
            lo[j] = f2bf(fv[j] - BF2F(uh));
        }
        const int base = row * 128 + (ch ^ (row & 7)) * 8;
        *(u16x8*)&xl[base] = hi;
        *(u16x8*)&xl[8192 + base] = lo;
    }
    __syncthreads();

    // ---- per-wave tile & A-fragments (held in regs for all 4 matrices) ----
    const int lane = t & 63, wid = t >> 6;
    const int r = lane & 31, g = lane >> 5;
    const int nt = (wid & 1) * 32;        // node offset in tile
    const int cb = (wid >> 1) * 64;       // col base
    s16x8 ah[8], al[8];
    {
        const int row = nt + r;
        const int s = row & 7;
        const int rb = row * 128;
        #pragma unroll
        for (int kc = 0; kc < 8; ++kc) {
            const int idx = rb + (((kc << 1) | g) ^ s) * 8;
            ah[kc] = *(const s16x8*)&xl[idx];
            al[kc] = *(const s16x8*)&xl[8192 + idx];
        }
    }
    const int col0 = cb + r, col1 = cb + 32 + r;
    const int wb0 = col0 * 128, ws0 = col0 & 7;
    const int wb1 = col1 * 128, ws1 = col1 & 7;

    for (int m = 0; m < 4; ++m) {
        f32x16 acc0, acc1;
        #pragma unroll
        for (int j = 0; j < 16; ++j) { acc0[j] = 0.f; acc1[j] = 0.f; }

        #pragma unroll
        for (int part = 0; part < 2; ++part) {
            __syncthreads();
            const u16x8* Wg = (const u16x8*)((part == 0 ? wHg : wLg) + m * 16384);
            for (int i = t; i < 2048; i += 256) {    // 128 rows x 16 chunks
                const int row = i >> 4, ch = i & 15;
                *(u16x8*)&wsm[row * 128 + (ch ^ (row & 7)) * 8] = Wg[i];
            }
            __syncthreads();
            #pragma unroll
            for (int kc = 0; kc < 8; ++kc) {
                const s16x8 b0 = *(const s16x8*)&wsm[wb0 + (((kc << 1) | g) ^ ws0) * 8];
                const s16x8 b1 = *(const s16x8*)&wsm[wb1 + (((kc << 1) | g) ^ ws1) * 8];
                acc0 = __builtin_amdgcn_mfma_f32_32x32x16_bf16(ah[kc], b0, acc0, 0, 0, 0);
                acc1 = __builtin_amdgcn_mfma_f32_32x32x16_bf16(ah[kc], b1, acc1, 0, 0, 0);
                if (part == 0) {
                    acc0 = __builtin_amdgcn_mfma_f32_32x32x16_bf16(al[kc], b0, acc0, 0, 0, 0);
                    acc1 = __builtin_amdgcn_mfma_f32_32x32x16_bf16(al[kc], b1, acc1, 0, 0, 0);
                }
            }
        }

        // ---- epilogue ----
        const float* bp;
        switch (m) {
            case 0:  bp = bq; break;
            case 1:  bp = bk; break;
            case 2:  bp = bv; break;
            default: bp = bs; break;
        }
        const float b0 = bp[col0], b1 = bp[col1];
        if (m == 0 || m == 3) {
            float* outp = (m == 0) ? q : xs;
            #pragma unroll
            for (int reg = 0; reg < 16; ++reg) {
                const int node = n0 + nt + (reg & 3) + 8 * (reg >> 2) + 4 * g;
                if (node < NN) {
                    outp[node * 128 + col0] = acc0[reg] + b0;
                    outp[node * 128 + col1] = acc1[reg] + b1;
                }
            }
        } else {
            const int koff = (m == 1) ? 0 : 16;      // k at +0, v at +16 (ushorts)
            const int o0 = (col0 >> 4) * 32 + koff + (col0 & 15);
            const int o1 = (col1 >> 4) * 32 + koff + (col1 & 15);
            #pragma unroll
            for (int reg = 0; reg < 16; ++reg) {
                const int node = n0 + nt + (reg & 3) + 8 * (reg >> 2) + 4 * g;
                if (node < NN) {
                    kvb[(size_t)node * 256 + o0] = f2bf(acc0[reg] + b0);
                    kvb[(size_t)node * 256 + o1] = f2bf(acc1[reg] + b1);
                }
            }
        }
    }
}

// ---------------------------------------------------------------- attention (CSR, online softmax)
__global__ __launch_bounds__(256)
void attn_kernel(const float* __restrict__ q, const uint4* __restrict__ kv4,
                 float* __restrict__ xio,
                 const int* __restrict__ offs, const int* __restrict__ csrc) {
    const int t = threadIdx.x;
    const int h = t & 7;
    const int n = blockIdx.x * 32 + (t >> 3);
    if (n >= NN) return;
    const float4* qp = (const float4*)(q + n * 128 + h * 16);
    const float4 q0 = qp[0], q1 = qp[1], q2 = qp[2], q3 = qp[3];
    float m = -__builtin_inff();
    float d = 0.f;
    float4 a0 = {}, a1 = {}, a2 = {}, a3 = {};
    const int e0 = offs[n], e1 = offs[n + 1];
    for (int e = e0; e < e1; ++e) {
        const int s = csrc[e];
        const uint4* kvp = kv4 + (size_t)s * 32 + h * 4;   // 512B row, 64B per head
        const uint4 ka = kvp[0], kb = kvp[1];              // k: 16 bf16
        float dot =
            q0.x * B2F_LO(ka.x) + q0.y * B2F_HI(ka.x) + q0.z * B2F_LO(ka.y) + q0.w * B2F_HI(ka.y)
          + q1.x * B2F_LO(ka.z) + q1.y * B2F_HI(ka.z) + q1.z * B2F_LO(ka.w) + q1.w * B2F_HI(ka.w)
          + q2.x * B2F_LO(kb.x) + q2.y * B2F_HI(kb.x) + q2.z * B2F_LO(kb.y) + q2.w * B2F_HI(kb.y)
          + q3.x * B2F_LO(kb.z) + q3.y * B2F_HI(kb.z) + q3.z * B2F_LO(kb.w) + q3.w * B2F_HI(kb.w);
        const float alpha = dot * 0.25f;                   // / sqrt(C=16)
        const float nm = fmaxf(m, alpha);
        const float scale = __expf(m - nm);                // 0 on first edge
        const float p = __expf(alpha - nm);
        d = d * scale + p;
        const uint4 va = kvp[2], vb = kvp[3];              // v: 16 bf16
        a0.x = a0.x * scale + p * B2F_LO(va.x); a0.y = a0.y * scale + p * B2F_HI(va.x);
        a0.z = a0.z * scale + p * B2F_LO(va.y); a0.w = a0.w * scale + p * B2F_HI(va.y);
        a1.x = a1.x * scale + p * B2F_LO(va.z); a1.y = a1.y * scale + p * B2F_HI(va.z);
        a1.z = a1.z * scale + p * B2F_LO(va.w); a1.w = a1.w * scale + p * B2F_HI(va.w);
        a2.x = a2.x * scale + p * B2F_LO(vb.x); a2.y = a2.y * scale + p * B2F_HI(vb.x);
        a2.z = a2.z * scale + p * B2F_LO(vb.y); a2.w = a2.w * scale + p * B2F_HI(vb.y);
        a3.x = a3.x * scale + p * B2F_LO(vb.z); a3.y = a3.y * scale + p * B2F_HI(vb.z);
        a3.z = a3.z * scale + p * B2F_LO(vb.w); a3.w = a3.w * scale + p * B2F_HI(vb.w);
        m = nm;
    }
    const float inv = 1.f / (d + 1e-16f);
    float4* op = (float4*)(xio + n * 128 + h * 16);
    float4 o0 = op[0], o1 = op[1], o2 = op[2], o3 = op[3];
    o0.x += a0.x * inv; o0.y += a0.y * inv; o0.z += a0.z * inv; o0.w += a0.w * inv;
    o1.x += a1.x * inv; o1.y += a1.y * inv; o1.z += a1.z * inv; o1.w += a1.w * inv;
    o2.x += a2.x * inv; o2.y += a2.y * inv; o2.z += a2.z * inv; o2.w += a2.w * inv;
    o3.x += a3.x * inv; o3.y += a3.y * inv; o3.z += a3.z * inv; o3.w += a3.w * inv;
    op[0] = o0; op[1] = o1; op[2] = o2; op[3] = o3;
}

// ---------------------------------------------------------------- readout (2-phase, fused gate)
__global__ __launch_bounds__(128)
void pool_partial(const float* __restrict__ x, const float* __restrict__ wg,
                  const float* __restrict__ bg, const int* __restrict__ starts,
                  float* __restrict__ psum, float* __restrict__ pmax) {
    const int g  = blockIdx.x / PCH;
    const int ch = blockIdx.x % PCH;
    const int c  = threadIdx.x;
    const int s0 = starts[g], s1 = starts[g + 1];
    const int total = s1 - s0;
    const int len = (total + PCH - 1) / PCH;
    const int n0 = s0 + ch * len;
    const int n1 = min(n0 + len, s1);
    const float w = wg[c];
    const float b = bg[0];
    __shared__ float red[2];
    float sum = 0.f, mx = -__builtin_inff();
    for (int n = n0; n < n1; ++n) {
        const float xv = x[n * 128 + c];
        float p = xv * w;
        #pragma unroll
        for (int o = 32; o; o >>= 1) p += __shfl_xor(p, o);
        if ((c & 63) == 0) red[c >> 6] = p;
        __syncthreads();
        const float dot = red[0] + red[1];
        __syncthreads();
        const float score = 1.f / (1.f + __expf(-(dot + b)));
        sum += score * xv;
        mx = fmaxf(mx, xv);
    }
    psum[blockIdx.x * 128 + c] = sum;
    pmax[blockIdx.x * 128 + c] = mx;
}

__global__ __launch_bounds__(128)
void pool_final(const float* __restrict__ psum, const float* __restrict__ pmax,
                float* __restrict__ out) {
    const int g = blockIdx.x, c = threadIdx.x;
    float s = 0.f, m = -__builtin_inff();
    #pragma unroll
    for (int ch = 0; ch < PCH; ++ch) {
        s += psum[(g * PCH + ch) * 128 + c];
        m = fmaxf(m, pmax[(g * PCH + ch) * 128 + c]);
    }
    out[g * 256 + c] = s;
    out[g * 256 + 128 + c] = m;
}

// ---------------------------------------------------------------- launch
extern "C" void kernel_launch(void* const* d_in, const int* in_sizes, int n_in,
                              void* d_out, int out_size, void* d_ws, size_t ws_size,
                              hipStream_t stream) {
    const float* x     = (const float*)d_in[0];
    const int*   ei    = (const int*)d_in[1];
    const int*   batch = (const int*)d_in[2];
    const float* Wq = (const float*)d_in[3];
    const float* bq = (const float*)d_in[4];
    const float* Wk = (const float*)d_in[5];
    const float* bk = (const float*)d_in[6];
    const float* Wv = (const float*)d_in[7];
    const float* bv = (const float*)d_in[8];
    const float* Ws = (const float*)d_in[9];
    const float* bs = (const float*)d_in[10];
    const float* wg = (const float*)d_in[11];
    const float* bg = (const float*)d_in[12];
    float* out = (float*)d_out;

    char* w = (char*)d_ws;
    float* qb            = (float*)w;          w += (size_t)NN * 128 * 4;
    unsigned short* kvb  = (unsigned short*)w; w += (size_t)NN * 256 * 2;
    float* bufA          = (float*)w;          w += (size_t)NN * 128 * 4;
    float* bufB          = (float*)w;          w += (size_t)NN * 128 * 4;
    float* psum          = (float*)w;          w += (size_t)GG * PCH * 128 * 4;
    float* pmax          = (float*)w;          w += (size_t)GG * PCH * 128 * 4;
    unsigned short* wtbh = (unsigned short*)w; w += (size_t)12 * 16384 * 2;
    unsigned short* wtbl = (unsigned short*)w; w += (size_t)12 * 16384 * 2;
    int* counts          = (int*)w;            w += (size_t)NN * 4;
    int* offsets         = (int*)w;            w += (size_t)(NN + 1) * 4;
    int* bsums           = (int*)w;            w += (size_t)256 * 4;
    int* csrc            = (int*)w;            w += (size_t)EE * 4;
    int* starts          = (int*)w;            w += (size_t)(GG + 1) * 4;

    const int* srcI = ei;
    const int* dstI = ei + EE;

    // CSR over dst (reused by all 3 layers) + weight prep
    hipMemsetAsync(counts, 0, (size_t)NN * 4, stream);
    hist_kernel<<<(EE + 255) / 256, 256, 0, stream>>>(dstI, counts);
    block_scan<<<SCB, 256, 0, stream>>>(counts, offsets, bsums);
    scan_sums<<<1, 256, 0, stream>>>(bsums);
    add_base<<<SCB, 256, 0, stream>>>(offsets, bsums);
    hipMemsetAsync(counts, 0, (size_t)NN * 4, stream);  // reuse as cursor
    scatter_kernel<<<(EE + 255) / 256, 256, 0, stream>>>(srcI, dstI, offsets, counts, csrc);
    starts_kernel<<<(NN + 256) / 256, 256, 0, stream>>>(batch, starts);
    prep_weights<<<dim3(12, 8), 256, 0, stream>>>(Wq, Wk, Wv, Ws, wtbh, wtbl);

    const float* xin = x;
    float* bufs[2] = {bufA, bufB};
    const int gemmBlocks = (NN + 63) / 64;   // 782
    const int attnBlocks = (NN + 31) / 32;   // 1563
    for (int l = 0; l < 3; ++l) {
        float* xs = bufs[l & 1];
        gemm_mfma<<<gemmBlocks, 256, 0, stream>>>(
            xin, wtbh + (size_t)l * 4 * 16384, wtbl + (size_t)l * 4 * 16384,
            bq + (size_t)l * 128, bk + (size_t)l * 128,
            bv + (size_t)l * 128, bs + (size_t)l * 128,
            qb, kvb, xs);
        attn_kernel<<<attnBlocks, 256, 0, stream>>>(qb, (const uint4*)kvb, xs, offsets, csrc);
        xin = xs;
    }

    pool_partial<<<GG * PCH, 128, 0, stream>>>(xin, wg, bg, starts, psum, pmax);
    pool_final<<<GG, 128, 0, stream>>>(psum, pmax, out);
}